// Round 25
// baseline (183.053 us; speedup 1.0000x reference)
//
#include <hip/hip_runtime.h>

#define B_ 32
#define C_ 256
#define T_ 2048
#define N_ 65536      // B_*T_
#define NE_ 1024
#define NELEM 16777216  // B_*C_*T_
#define TAU 1.75e-4f    // repair window: np fp32 quantization (~3.2e-5) + f16 GEMM noise, >1.5x margin
#define WLCAP 8192
#define RPB 8           // rows per repair group

typedef _Float16 half8 __attribute__((ext_vector_type(8)));
typedef float f32x4 __attribute__((ext_vector_type(4)));

// d_ws layout (4-byte units):
// [0,1024)            counts (int)
// [1024,2048)         enorm (float)
// [2048]              sse (float)
// [2049]              nflag (int)
// [2056,18440)        keys (u64 x WLCAP; init 0xFF)
// [18440,83976)       idx (int)
// [83976,92168)       worklist (int)
// [92168,100360)      szf (float x WLCAP)
// [100360,231432)     ebuf: e as f16 in 16x16x32 MFMA B-fragment order (512 KB)
// [231432,493576)     et: e transposed fp32 [k][code] (1 MB)
// [493576,2590728)    zstage (float x WLCAP x 256)
// [2590728,2656264)   scores (float x N_, dead store kept for k_vq codegen stability)

// One init dispatch replaces the memsets.
__global__ void k_init(unsigned int* __restrict__ ws) {
  int i = blockIdx.x * blockDim.x + threadIdx.x;
  if (i < 18440) ws[i] = (i < 2056) ? 0u : 0xFFFFFFFFu;
}

// Standalone prep (r18 form): per-code ebuf/enorm/et.
__global__ void k_prep(const float* __restrict__ emb, half8* __restrict__ ebuf,
                       float* __restrict__ enorm, float* __restrict__ et) {
  int code = blockIdx.x * blockDim.x + threadIdx.x;  // 0..1023
  const float4* row = reinterpret_cast<const float4*>(emb + (size_t)code * C_);
  double sum = 0.0;
#pragma unroll
  for (int k = 0; k < C_ / 4; ++k) {
    float4 v = row[k];
    sum = fma((double)v.x, (double)v.x, sum);
    sum = fma((double)v.y, (double)v.y, sum);
    sum = fma((double)v.z, (double)v.z, sum);
    sum = fma((double)v.w, (double)v.w, sum);
    et[(k * 4 + 0) * NE_ + code] = v.x;
    et[(k * 4 + 1) * NE_ + code] = v.y;
    et[(k * 4 + 2) * NE_ + code] = v.z;
    et[(k * 4 + 3) * NE_ + code] = v.w;
  }
  enorm[code] = (float)sum;
  const int ct = code >> 4, c = code & 15;
#pragma unroll
  for (int s = 0; s < 8; ++s) {
#pragma unroll
    for (int g = 0; g < 4; ++g) {
      float4 v0 = row[s * 8 + g * 2];
      float4 v1 = row[s * 8 + g * 2 + 1];
      half8 hv;
      hv[0] = (_Float16)v0.x; hv[1] = (_Float16)v0.y;
      hv[2] = (_Float16)v0.z; hv[3] = (_Float16)v0.w;
      hv[4] = (_Float16)v1.x; hv[5] = (_Float16)v1.y;
      hv[6] = (_Float16)v1.z; hv[7] = (_Float16)v1.w;
      ebuf[(ct * 8 + s) * 64 + g * 16 + c] = hv;
    }
  }
}

// MFMA VQ (hi-only f16, 16x16x32): r24 structure with register double-buffered
// B prefetch, distance 2. Two named buffer sets P/Q (128 VGPRs) are forced
// live simultaneously -> all 16 loads of a batch stay in flight with a full
// iteration (~1.7k cyc) of MFMA/fold cover. Per-(row,code) MFMA sequences,
// fold order and merge bit-identical to r24; only load timing changes.
__launch_bounds__(256, 2)
__global__ void k_vq(const float* __restrict__ z, const half8* __restrict__ ebuf,
                     const float* __restrict__ enorm, int* __restrict__ idx_i,
                     float* __restrict__ idx_f, int* __restrict__ counts,
                     int* __restrict__ nflag, int* __restrict__ worklist,
                     float* __restrict__ score_out) {
  const int tid = threadIdx.x;
  const int w = tid >> 6;
  const int l = tid & 63;
  const int col = l & 15;
  const int g = l >> 4;
  const int n0 = blockIdx.x * 128;
  const int b = n0 >> 11;
  const int t0 = (n0 & (T_ - 1)) + w * 32;
  const float* zc0 = z + (size_t)b * C_ * T_ + t0 + col;
  const float* zc1 = zc0 + 16;

  half8 A0[8], A1[8];
#pragma unroll
  for (int s = 0; s < 8; ++s) {
    half8 h0, h1;
#pragma unroll
    for (int i = 0; i < 8; ++i) {
      const size_t ko = (size_t)(32 * s + 8 * g + i) * T_;
      h0[i] = (_Float16)zc0[ko];
      h1[i] = (_Float16)zc1[ko];
    }
    A0[s] = h0; A1[s] = h1;
  }

  float b1s[2][4], b2s[2][4]; int b1i[2][4];
#pragma unroll
  for (int rt = 0; rt < 2; ++rt)
#pragma unroll
    for (int q = 0; q < 4; ++q) { b1s[rt][q] = 3.4e38f; b2s[rt][q] = 3.4e38f; b1i[rt][q] = 0; }

  auto fold = [&](const f32x4& c00, const f32x4& c10, const f32x4& c01, const f32x4& c11,
                  float en0, float en1, int cb0, int cb1) {
#pragma unroll
    for (int q = 0; q < 4; ++q) {
      {
        float sc = fmaf(-2.f, c00[q], en0);
        float nb2 = fminf(b2s[0][q], fmaxf(b1s[0][q], sc));
        bool lt = sc < b1s[0][q];
        b2s[0][q] = nb2; b1i[0][q] = lt ? cb0 : b1i[0][q]; b1s[0][q] = fminf(b1s[0][q], sc);
      }
      {
        float sc = fmaf(-2.f, c10[q], en0);
        float nb2 = fminf(b2s[1][q], fmaxf(b1s[1][q], sc));
        bool lt = sc < b1s[1][q];
        b2s[1][q] = nb2; b1i[1][q] = lt ? cb0 : b1i[1][q]; b1s[1][q] = fminf(b1s[1][q], sc);
      }
      {
        float sc = fmaf(-2.f, c01[q], en1);
        float nb2 = fminf(b2s[0][q], fmaxf(b1s[0][q], sc));
        bool lt = sc < b1s[0][q];
        b2s[0][q] = nb2; b1i[0][q] = lt ? cb1 : b1i[0][q]; b1s[0][q] = fminf(b1s[0][q], sc);
      }
      {
        float sc = fmaf(-2.f, c11[q], en1);
        float nb2 = fminf(b2s[1][q], fmaxf(b1s[1][q], sc));
        bool lt = sc < b1s[1][q];
        b2s[1][q] = nb2; b1i[1][q] = lt ? cb1 : b1i[1][q]; b1s[1][q] = fminf(b1s[1][q], sc);
      }
    }
  };

  const half8* bp = ebuf + l;
  half8 P0[8], P1[8], Q0[8], Q1[8];
  // prologue: P <- ctp 0, Q <- ctp 1
#pragma unroll
  for (int s = 0; s < 8; ++s) { P0[s] = bp[s * 64]; P1[s] = bp[(8 + s) * 64]; }
#pragma unroll
  for (int s = 0; s < 8; ++s) { Q0[s] = bp[(16 + s) * 64]; Q1[s] = bp[(24 + s) * 64]; }
  const f32x4 zero4 = {0.f, 0.f, 0.f, 0.f};

  for (int ctp = 0; ctp < 32; ctp += 2) {
    // even half: consume P (ctp), reload P <- ctp+2
    {
      f32x4 a00 = zero4, a01 = zero4, a10 = zero4, a11 = zero4;
#pragma unroll
      for (int s = 0; s < 8; ++s) {
        a00 = __builtin_amdgcn_mfma_f32_16x16x32_f16(A0[s], P0[s], a00, 0, 0, 0);
        a10 = __builtin_amdgcn_mfma_f32_16x16x32_f16(A1[s], P0[s], a10, 0, 0, 0);
      }
      if (ctp + 2 < 32) {
#pragma unroll
        for (int s = 0; s < 8; ++s) P0[s] = bp[((ctp + 2) * 16 + s) * 64];
      }
#pragma unroll
      for (int s = 0; s < 8; ++s) {
        a01 = __builtin_amdgcn_mfma_f32_16x16x32_f16(A0[s], P1[s], a01, 0, 0, 0);
        a11 = __builtin_amdgcn_mfma_f32_16x16x32_f16(A1[s], P1[s], a11, 0, 0, 0);
      }
      if (ctp + 2 < 32) {
#pragma unroll
        for (int s = 0; s < 8; ++s) P1[s] = bp[((ctp + 2) * 16 + 8 + s) * 64];
      }
      const float en0 = enorm[ctp * 32 + col];
      const float en1 = enorm[ctp * 32 + 16 + col];
      fold(a00, a10, a01, a11, en0, en1, ctp * 32 + col, ctp * 32 + 16 + col);
    }
    // odd half: consume Q (ctp+1), reload Q <- ctp+3
    {
      f32x4 a00 = zero4, a01 = zero4, a10 = zero4, a11 = zero4;
#pragma unroll
      for (int s = 0; s < 8; ++s) {
        a00 = __builtin_amdgcn_mfma_f32_16x16x32_f16(A0[s], Q0[s], a00, 0, 0, 0);
        a10 = __builtin_amdgcn_mfma_f32_16x16x32_f16(A1[s], Q0[s], a10, 0, 0, 0);
      }
      if (ctp + 3 < 32) {
#pragma unroll
        for (int s = 0; s < 8; ++s) Q0[s] = bp[((ctp + 3) * 16 + s) * 64];
      }
#pragma unroll
      for (int s = 0; s < 8; ++s) {
        a01 = __builtin_amdgcn_mfma_f32_16x16x32_f16(A0[s], Q1[s], a01, 0, 0, 0);
        a11 = __builtin_amdgcn_mfma_f32_16x16x32_f16(A1[s], Q1[s], a11, 0, 0, 0);
      }
      if (ctp + 3 < 32) {
#pragma unroll
        for (int s = 0; s < 8; ++s) Q1[s] = bp[((ctp + 3) * 16 + 8 + s) * 64];
      }
      const float en0 = enorm[(ctp + 1) * 32 + col];
      const float en1 = enorm[(ctp + 1) * 32 + 16 + col];
      fold(a00, a10, a01, a11, en0, en1, (ctp + 1) * 32 + col, (ctp + 1) * 32 + 16 + col);
    }
  }

#pragma unroll
  for (int m = 1; m < 16; m <<= 1) {
#pragma unroll
    for (int rt = 0; rt < 2; ++rt)
#pragma unroll
      for (int q = 0; q < 4; ++q) {
        float o1 = __shfl_xor(b1s[rt][q], m);
        int oi = __shfl_xor(b1i[rt][q], m);
        float o2 = __shfl_xor(b2s[rt][q], m);
        float hi = fmaxf(b1s[rt][q], o1);
        b2s[rt][q] = fminf(fminf(b2s[rt][q], o2), hi);
        if (o1 < b1s[rt][q] || (o1 == b1s[rt][q] && oi < b1i[rt][q])) {
          b1s[rt][q] = o1; b1i[rt][q] = oi;
        }
      }
  }
  if (col == 0) {
#pragma unroll
    for (int rt = 0; rt < 2; ++rt)
#pragma unroll
      for (int q = 0; q < 4; ++q) {
        // C/D map (m89): row = g*4 + q
        int n = n0 + w * 32 + rt * 16 + g * 4 + q;
        idx_i[n] = b1i[rt][q];
        idx_f[n] = (float)b1i[rt][q];
        score_out[n] = b1s[rt][q];
        atomicAdd(&counts[b1i[rt][q]], 1);
        if (b2s[rt][q] - b1s[rt][q] < TAU) {
          int p = atomicAdd(nflag, 1);
          if (p < WLCAP) worklist[p] = n;
        }
      }
  }
}

// Stage flagged rows' z columns (scattered read ONCE per row) + szf.
__global__ void k_zstage(const float* __restrict__ z, const int* __restrict__ nflag,
                         const int* __restrict__ worklist, float* __restrict__ zstage,
                         float* __restrict__ szfbuf) {
  __shared__ double wred[4];
  const int tid = threadIdx.x;
  int cnt = nflag[0];
  if (cnt > WLCAP) cnt = WLCAP;
  for (int wi = blockIdx.x; wi < cnt; wi += gridDim.x) {
    int n = worklist[wi];
    int b = n >> 11, t = n & (T_ - 1);
    float zv = z[(size_t)b * C_ * T_ + (size_t)tid * T_ + t];
    zstage[(size_t)wi * C_ + tid] = zv;
    double p = (double)zv * (double)zv;
#pragma unroll
    for (int m = 32; m > 0; m >>= 1) p += __shfl_down(p, m);
    if ((tid & 63) == 0) wred[tid >> 6] = p;
    __syncthreads();
    if (tid == 0)
      szfbuf[wi] = (float)(wred[0] + wred[1] + wred[2] + wred[3]);
    __syncthreads();
  }
}

// Re-score flagged rows emulating numpy's fp32 arithmetic.  [r18, byte-exact]
__global__ void k_repair(const float* __restrict__ zstage, const float* __restrict__ szfbuf,
                         const float* __restrict__ et, const float* __restrict__ enorm,
                         const int* __restrict__ nflag, const int* __restrict__ worklist,
                         unsigned long long* __restrict__ keys) {
  __shared__ float zs[RPB][C_];
  __shared__ unsigned long long kred[RPB][256];
  const int tid = threadIdx.x;
  int cnt = nflag[0];
  if (cnt > WLCAP) cnt = WLCAP;
  const int ngroups = (cnt + RPB - 1) / RPB;
  const int nunits = ngroups * 4;
  for (int u = blockIdx.x; u < nunits; u += gridDim.x) {
    const int grp = u >> 2;
    const int quarter = u & 3;
    const int base = grp * RPB;
#pragma unroll
    for (int r = 0; r < RPB; ++r) {
      int wi = base + r; if (wi >= cnt) wi = cnt - 1;
      zs[r][tid] = zstage[(size_t)wi * C_ + tid];
    }
    __syncthreads();
    const int j = quarter * 256 + tid;
    float acc[RPB];
#pragma unroll
    for (int r = 0; r < RPB; ++r) acc[r] = 0.f;
#pragma unroll 4
    for (int k4 = 0; k4 < C_ / 4; ++k4) {
      float e0 = et[(k4 * 4 + 0) * NE_ + j];
      float e1 = et[(k4 * 4 + 1) * NE_ + j];
      float e2 = et[(k4 * 4 + 2) * NE_ + j];
      float e3 = et[(k4 * 4 + 3) * NE_ + j];
#pragma unroll
      for (int r = 0; r < RPB; ++r) {
        acc[r] = fmaf(zs[r][k4 * 4 + 0], e0, acc[r]);
        acc[r] = fmaf(zs[r][k4 * 4 + 1], e1, acc[r]);
        acc[r] = fmaf(zs[r][k4 * 4 + 2], e2, acc[r]);
        acc[r] = fmaf(zs[r][k4 * 4 + 3], e3, acc[r]);
      }
    }
    const float en = enorm[j];
#pragma unroll
    for (int r = 0; r < RPB; ++r) {
      int wi = base + r; if (wi >= cnt) wi = cnt - 1;
      float X = szfbuf[wi] + en;
      float Y = 2.0f * acc[r];
      float d = X - Y;
      unsigned int du = __float_as_uint(d);
      unsigned int sortable = (du & 0x80000000u) ? ~du : (du | 0x80000000u);
      kred[r][tid] = ((unsigned long long)sortable << 32) | (unsigned int)j;
    }
    __syncthreads();
    for (int o = 128; o > 0; o >>= 1) {
      if (tid < o) {
#pragma unroll
        for (int r = 0; r < RPB; ++r) {
          unsigned long long ok = kred[r][tid + o];
          if (ok < kred[r][tid]) kred[r][tid] = ok;
        }
      }
      __syncthreads();
    }
    if (tid < RPB && base + tid < cnt)
      atomicMin(&keys[base + tid], kred[tid][0]);
    __syncthreads();
  }
}

// Apply repair winners to idx / counts.
__global__ void k_fix(const int* __restrict__ nflag, const int* __restrict__ worklist,
                      const unsigned long long* __restrict__ keys,
                      int* __restrict__ idx_i, float* __restrict__ idx_f,
                      int* __restrict__ counts) {
  int cnt = nflag[0];
  if (cnt > WLCAP) cnt = WLCAP;
  int wi = blockIdx.x * blockDim.x + threadIdx.x;
  if (wi < cnt) {
    int n = worklist[wi];
    unsigned long long key = keys[wi];
    int nw = (int)(key & 0xFFFFFFFFull);
    int old = idx_i[n];
    if (nw != old) {
      idx_i[n] = nw; idx_f[n] = (float)nw;
      atomicAdd(&counts[old], -1);
      atomicAdd(&counts[nw], 1);
    }
  }
}

// Tiled gather fused with direct SSE. Write-out vectorized (r24 form).
__launch_bounds__(256, 4)
__global__ void k_gather(const float* __restrict__ z, const float* __restrict__ emb,
                         const int* __restrict__ idxv, float* __restrict__ zq,
                         float* __restrict__ sse) {
  __shared__ int ids[32];
  __shared__ float tile[32 * 260];
  __shared__ float wsum[4];
  const int tid = threadIdx.x;
  const int blk = blockIdx.x;
  const int b = blk >> 6;
  const int t0 = (blk & 63) << 5;
  const int n0 = (b << 11) + t0;
  if (tid < 32) ids[tid] = idxv[n0 + tid];
  __syncthreads();
  const int r = tid & 31;
  const int q = tid >> 5;
  {
    const float4* er = reinterpret_cast<const float4*>(emb) + ((size_t)ids[r] << 6) + (q << 3);
    float4* dst = reinterpret_cast<float4*>(&tile[r * 260 + (q << 5)]);
#pragma unroll
    for (int j = 0; j < 8; ++j) dst[j] = er[j];
  }
  __syncthreads();
  const int r4 = tid & 7;
  const int c0 = tid >> 3;
  float local = 0.f;
  const size_t base = (((size_t)b << 8) << 11) + t0;
  const float4* z4 = reinterpret_cast<const float4*>(z);
  float4* zq4 = reinterpret_cast<float4*>(zq);
#pragma unroll
  for (int jc = 0; jc < 8; ++jc) {
    const int c = c0 + (jc << 5);
    float4 qv;
    qv.x = tile[(4 * r4 + 0) * 260 + c];
    qv.y = tile[(4 * r4 + 1) * 260 + c];
    qv.z = tile[(4 * r4 + 2) * 260 + c];
    qv.w = tile[(4 * r4 + 3) * 260 + c];
    const size_t g4 = ((base + ((size_t)c << 11)) >> 2) + r4;
    float4 zv = z4[g4];
    zq4[g4] = qv;
    float dx = qv.x - zv.x, dy = qv.y - zv.y, dz = qv.z - zv.z, dw = qv.w - zv.w;
    local = fmaf(dx, dx, local); local = fmaf(dy, dy, local);
    local = fmaf(dz, dz, local); local = fmaf(dw, dw, local);
  }
#pragma unroll
  for (int m = 32; m > 0; m >>= 1) local += __shfl_down(local, m);
  if ((tid & 63) == 0) wsum[tid >> 6] = local;
  __syncthreads();
  if (tid == 0) atomicAdd(sse, wsum[0] + wsum[1] + wsum[2] + wsum[3]);
}

__global__ void k_final(const int* __restrict__ counts, const float* __restrict__ sse,
                        float* __restrict__ out_loss, float* __restrict__ out_perp) {
  __shared__ float red[256];
  int tid = threadIdx.x;
  float s = 0.f;
  for (int j = tid; j < NE_; j += 256) {
    float em = (float)counts[j] * (1.0f / (float)N_);
    s += em * logf(em + 1e-10f);
  }
  red[tid] = s;
  __syncthreads();
  for (int o = 128; o > 0; o >>= 1) {
    if (tid < o) red[tid] += red[tid + o];
    __syncthreads();
  }
  if (tid == 0) {
    out_perp[0] = expf(-red[0]);
    out_loss[0] = (0.25f + 1.0f) * sse[0] / (float)NELEM;
  }
}

extern "C" void kernel_launch(void* const* d_in, const int* in_sizes, int n_in,
                              void* d_out, int out_size, void* d_ws, size_t ws_size,
                              hipStream_t stream) {
  const float* z = (const float*)d_in[0];
  const float* emb = (const float*)d_in[1];
  float* out = (float*)d_out;
  float* zq_out = out;
  float* out_loss = out + NELEM;
  float* out_perp = out + NELEM + 1;
  float* out_idx = out + NELEM + 2;

  int* ws_counts = (int*)d_ws;
  float* ws_enorm = (float*)d_ws + 1024;
  float* ws_sse = (float*)d_ws + 2048;
  int* ws_nflag = (int*)d_ws + 2049;
  unsigned long long* ws_keys = (unsigned long long*)((float*)d_ws + 2056);
  int* ws_idx = (int*)d_ws + 18440;
  int* ws_worklist = (int*)d_ws + 83976;
  float* ws_szf = (float*)d_ws + 92168;
  half8* ws_ebuf = (half8*)((float*)d_ws + 100360);
  float* ws_et = (float*)d_ws + 231432;
  float* ws_zstage = (float*)d_ws + 493576;
  float* ws_scores = (float*)d_ws + 2590728;

  k_init<<<73, 256, 0, stream>>>((unsigned int*)d_ws);
  k_prep<<<NE_ / 64, 64, 0, stream>>>(emb, ws_ebuf, ws_enorm, ws_et);
  k_vq<<<N_ / 128, 256, 0, stream>>>(z, ws_ebuf, ws_enorm, ws_idx, out_idx,
                                     ws_counts, ws_nflag, ws_worklist, ws_scores);
  k_zstage<<<2048, 256, 0, stream>>>(z, ws_nflag, ws_worklist, ws_zstage, ws_szf);
  k_repair<<<2048, 256, 0, stream>>>(ws_zstage, ws_szf, ws_et, ws_enorm,
                                     ws_nflag, ws_worklist, ws_keys);
  k_fix<<<WLCAP / 256, 256, 0, stream>>>(ws_nflag, ws_worklist, ws_keys,
                                         ws_idx, out_idx, ws_counts);
  k_gather<<<2048, 256, 0, stream>>>(z, emb, ws_idx, zq_out, ws_sse);
  k_final<<<1, 256, 0, stream>>>(ws_counts, ws_sse, out_loss, out_perp);
}

// Round 26
// 171.398 us; speedup vs baseline: 1.0680x; 1.0680x over previous
//
#include <hip/hip_runtime.h>

#define B_ 32
#define C_ 256
#define T_ 2048
#define N_ 65536      // B_*T_
#define NE_ 1024
#define NELEM 16777216  // B_*C_*T_
#define TAU 1.75e-4f    // repair window: np fp32 quantization (~3.2e-5) + f16 GEMM noise, >1.5x margin
#define WLCAP 8192
#define RPB 8           // rows per repair group

typedef _Float16 half8 __attribute__((ext_vector_type(8)));
typedef float f32x4 __attribute__((ext_vector_type(4)));

// d_ws layout (4-byte units):
// [0,1024)            counts (int)
// [1024,2048)         enorm (float)
// [2048]              sse (float)
// [2049]              nflag (int)
// [2056,18440)        keys (u64 x WLCAP; init 0xFF)
// [18440,83976)       idx (int)
// [83976,92168)       worklist (int)
// [92168,100360)      szf (float x WLCAP)
// [100360,231432)     ebuf: e as f16 in 16x16x32 MFMA B-fragment order (512 KB)
// [231432,493576)     et: e transposed fp32 [k][code] (1 MB)
// [493576,2590728)    zstage (float x WLCAP x 256)
// [2590728,2656264)   scores (float x N_, dead store kept for k_vq codegen stability)

// One init dispatch replaces the memsets.
__global__ void k_init(unsigned int* __restrict__ ws) {
  int i = blockIdx.x * blockDim.x + threadIdx.x;
  if (i < 18440) ws[i] = (i < 2056) ? 0u : 0xFFFFFFFFu;
}

// Standalone prep (r18 form): per-code ebuf/enorm/et.
__global__ void k_prep(const float* __restrict__ emb, half8* __restrict__ ebuf,
                       float* __restrict__ enorm, float* __restrict__ et) {
  int code = blockIdx.x * blockDim.x + threadIdx.x;  // 0..1023
  const float4* row = reinterpret_cast<const float4*>(emb + (size_t)code * C_);
  double sum = 0.0;
#pragma unroll
  for (int k = 0; k < C_ / 4; ++k) {
    float4 v = row[k];
    sum = fma((double)v.x, (double)v.x, sum);
    sum = fma((double)v.y, (double)v.y, sum);
    sum = fma((double)v.z, (double)v.z, sum);
    sum = fma((double)v.w, (double)v.w, sum);
    et[(k * 4 + 0) * NE_ + code] = v.x;
    et[(k * 4 + 1) * NE_ + code] = v.y;
    et[(k * 4 + 2) * NE_ + code] = v.z;
    et[(k * 4 + 3) * NE_ + code] = v.w;
  }
  enorm[code] = (float)sum;
  const int ct = code >> 4, c = code & 15;
#pragma unroll
  for (int s = 0; s < 8; ++s) {
#pragma unroll
    for (int g = 0; g < 4; ++g) {
      float4 v0 = row[s * 8 + g * 2];
      float4 v1 = row[s * 8 + g * 2 + 1];
      half8 hv;
      hv[0] = (_Float16)v0.x; hv[1] = (_Float16)v0.y;
      hv[2] = (_Float16)v0.z; hv[3] = (_Float16)v0.w;
      hv[4] = (_Float16)v1.x; hv[5] = (_Float16)v1.y;
      hv[6] = (_Float16)v1.z; hv[7] = (_Float16)v1.w;
      ebuf[(ct * 8 + s) * 64 + g * 16 + c] = hv;
    }
  }
}

// MFMA VQ (hi-only f16, 16x16x32): byte-exact r18 passing kernel (VGPR 108).
__launch_bounds__(256, 2)
__global__ void k_vq(const float* __restrict__ z, const half8* __restrict__ ebuf,
                     const float* __restrict__ enorm, int* __restrict__ idx_i,
                     float* __restrict__ idx_f, int* __restrict__ counts,
                     int* __restrict__ nflag, int* __restrict__ worklist,
                     float* __restrict__ score_out) {
  const int tid = threadIdx.x;
  const int w = tid >> 6;
  const int l = tid & 63;
  const int col = l & 15;
  const int g = l >> 4;
  const int n0 = blockIdx.x * 128;
  const int b = n0 >> 11;
  const int t0 = (n0 & (T_ - 1)) + w * 32;
  const float* zc0 = z + (size_t)b * C_ * T_ + t0 + col;
  const float* zc1 = zc0 + 16;

  half8 A0[8], A1[8];
#pragma unroll
  for (int s = 0; s < 8; ++s) {
    half8 h0, h1;
#pragma unroll
    for (int i = 0; i < 8; ++i) {
      const size_t ko = (size_t)(32 * s + 8 * g + i) * T_;
      h0[i] = (_Float16)zc0[ko];
      h1[i] = (_Float16)zc1[ko];
    }
    A0[s] = h0; A1[s] = h1;
  }

  float b1s[2][4], b2s[2][4]; int b1i[2][4];
#pragma unroll
  for (int rt = 0; rt < 2; ++rt)
#pragma unroll
    for (int q = 0; q < 4; ++q) { b1s[rt][q] = 3.4e38f; b2s[rt][q] = 3.4e38f; b1i[rt][q] = 0; }

  auto fold = [&](const f32x4& c00, const f32x4& c10, const f32x4& c01, const f32x4& c11,
                  float en0, float en1, int cb0, int cb1) {
#pragma unroll
    for (int q = 0; q < 4; ++q) {
      {
        float sc = fmaf(-2.f, c00[q], en0);
        float nb2 = fminf(b2s[0][q], fmaxf(b1s[0][q], sc));
        bool lt = sc < b1s[0][q];
        b2s[0][q] = nb2; b1i[0][q] = lt ? cb0 : b1i[0][q]; b1s[0][q] = fminf(b1s[0][q], sc);
      }
      {
        float sc = fmaf(-2.f, c10[q], en0);
        float nb2 = fminf(b2s[1][q], fmaxf(b1s[1][q], sc));
        bool lt = sc < b1s[1][q];
        b2s[1][q] = nb2; b1i[1][q] = lt ? cb0 : b1i[1][q]; b1s[1][q] = fminf(b1s[1][q], sc);
      }
      {
        float sc = fmaf(-2.f, c01[q], en1);
        float nb2 = fminf(b2s[0][q], fmaxf(b1s[0][q], sc));
        bool lt = sc < b1s[0][q];
        b2s[0][q] = nb2; b1i[0][q] = lt ? cb1 : b1i[0][q]; b1s[0][q] = fminf(b1s[0][q], sc);
      }
      {
        float sc = fmaf(-2.f, c11[q], en1);
        float nb2 = fminf(b2s[1][q], fmaxf(b1s[1][q], sc));
        bool lt = sc < b1s[1][q];
        b2s[1][q] = nb2; b1i[1][q] = lt ? cb1 : b1i[1][q]; b1s[1][q] = fminf(b1s[1][q], sc);
      }
    }
  };

  const half8* bp = ebuf + l;
  half8 Bf0[8], Bf1[8];
#pragma unroll
  for (int s = 0; s < 8; ++s) { Bf0[s] = bp[s * 64]; Bf1[s] = bp[(8 + s) * 64]; }
  const f32x4 zero4 = {0.f, 0.f, 0.f, 0.f};

  for (int ctp = 0; ctp < 32; ++ctp) {
    f32x4 a00 = zero4, a01 = zero4, a10 = zero4, a11 = zero4;
#pragma unroll
    for (int s = 0; s < 8; ++s) {
      a00 = __builtin_amdgcn_mfma_f32_16x16x32_f16(A0[s], Bf0[s], a00, 0, 0, 0);
      a10 = __builtin_amdgcn_mfma_f32_16x16x32_f16(A1[s], Bf0[s], a10, 0, 0, 0);
    }
    if (ctp < 31) {
#pragma unroll
      for (int s = 0; s < 8; ++s) Bf0[s] = bp[((ctp + 1) * 16 + s) * 64];
    }
#pragma unroll
    for (int s = 0; s < 8; ++s) {
      a01 = __builtin_amdgcn_mfma_f32_16x16x32_f16(A0[s], Bf1[s], a01, 0, 0, 0);
      a11 = __builtin_amdgcn_mfma_f32_16x16x32_f16(A1[s], Bf1[s], a11, 0, 0, 0);
    }
    if (ctp < 31) {
#pragma unroll
      for (int s = 0; s < 8; ++s) Bf1[s] = bp[((ctp + 1) * 16 + 8 + s) * 64];
    }
    const float en0 = enorm[ctp * 32 + col];
    const float en1 = enorm[ctp * 32 + 16 + col];
    fold(a00, a10, a01, a11, en0, en1, ctp * 32 + col, ctp * 32 + 16 + col);
  }

#pragma unroll
  for (int m = 1; m < 16; m <<= 1) {
#pragma unroll
    for (int rt = 0; rt < 2; ++rt)
#pragma unroll
      for (int q = 0; q < 4; ++q) {
        float o1 = __shfl_xor(b1s[rt][q], m);
        int oi = __shfl_xor(b1i[rt][q], m);
        float o2 = __shfl_xor(b2s[rt][q], m);
        float hi = fmaxf(b1s[rt][q], o1);
        b2s[rt][q] = fminf(fminf(b2s[rt][q], o2), hi);
        if (o1 < b1s[rt][q] || (o1 == b1s[rt][q] && oi < b1i[rt][q])) {
          b1s[rt][q] = o1; b1i[rt][q] = oi;
        }
      }
  }
  if (col == 0) {
#pragma unroll
    for (int rt = 0; rt < 2; ++rt)
#pragma unroll
      for (int q = 0; q < 4; ++q) {
        // C/D map (m89): row = g*4 + q
        int n = n0 + w * 32 + rt * 16 + g * 4 + q;
        idx_i[n] = b1i[rt][q];
        idx_f[n] = (float)b1i[rt][q];
        score_out[n] = b1s[rt][q];
        atomicAdd(&counts[b1i[rt][q]], 1);
        if (b2s[rt][q] - b1s[rt][q] < TAU) {
          int p = atomicAdd(nflag, 1);
          if (p < WLCAP) worklist[p] = n;
        }
      }
  }
}

// Stage flagged rows' z columns (scattered read ONCE per row) + szf.
__global__ void k_zstage(const float* __restrict__ z, const int* __restrict__ nflag,
                         const int* __restrict__ worklist, float* __restrict__ zstage,
                         float* __restrict__ szfbuf) {
  __shared__ double wred[4];
  const int tid = threadIdx.x;
  int cnt = nflag[0];
  if (cnt > WLCAP) cnt = WLCAP;
  for (int wi = blockIdx.x; wi < cnt; wi += gridDim.x) {
    int n = worklist[wi];
    int b = n >> 11, t = n & (T_ - 1);
    float zv = z[(size_t)b * C_ * T_ + (size_t)tid * T_ + t];
    zstage[(size_t)wi * C_ + tid] = zv;
    double p = (double)zv * (double)zv;
#pragma unroll
    for (int m = 32; m > 0; m >>= 1) p += __shfl_down(p, m);
    if ((tid & 63) == 0) wred[tid >> 6] = p;
    __syncthreads();
    if (tid == 0)
      szfbuf[wi] = (float)(wred[0] + wred[1] + wred[2] + wred[3]);
    __syncthreads();
  }
}

// Re-score flagged rows emulating numpy's fp32 arithmetic.  [r18, byte-exact]
__global__ void k_repair(const float* __restrict__ zstage, const float* __restrict__ szfbuf,
                         const float* __restrict__ et, const float* __restrict__ enorm,
                         const int* __restrict__ nflag, const int* __restrict__ worklist,
                         unsigned long long* __restrict__ keys) {
  __shared__ float zs[RPB][C_];
  __shared__ unsigned long long kred[RPB][256];
  const int tid = threadIdx.x;
  int cnt = nflag[0];
  if (cnt > WLCAP) cnt = WLCAP;
  const int ngroups = (cnt + RPB - 1) / RPB;
  const int nunits = ngroups * 4;
  for (int u = blockIdx.x; u < nunits; u += gridDim.x) {
    const int grp = u >> 2;
    const int quarter = u & 3;
    const int base = grp * RPB;
#pragma unroll
    for (int r = 0; r < RPB; ++r) {
      int wi = base + r; if (wi >= cnt) wi = cnt - 1;
      zs[r][tid] = zstage[(size_t)wi * C_ + tid];
    }
    __syncthreads();
    const int j = quarter * 256 + tid;
    float acc[RPB];
#pragma unroll
    for (int r = 0; r < RPB; ++r) acc[r] = 0.f;
#pragma unroll 4
    for (int k4 = 0; k4 < C_ / 4; ++k4) {
      float e0 = et[(k4 * 4 + 0) * NE_ + j];
      float e1 = et[(k4 * 4 + 1) * NE_ + j];
      float e2 = et[(k4 * 4 + 2) * NE_ + j];
      float e3 = et[(k4 * 4 + 3) * NE_ + j];
#pragma unroll
      for (int r = 0; r < RPB; ++r) {
        acc[r] = fmaf(zs[r][k4 * 4 + 0], e0, acc[r]);
        acc[r] = fmaf(zs[r][k4 * 4 + 1], e1, acc[r]);
        acc[r] = fmaf(zs[r][k4 * 4 + 2], e2, acc[r]);
        acc[r] = fmaf(zs[r][k4 * 4 + 3], e3, acc[r]);
      }
    }
    const float en = enorm[j];
#pragma unroll
    for (int r = 0; r < RPB; ++r) {
      int wi = base + r; if (wi >= cnt) wi = cnt - 1;
      float X = szfbuf[wi] + en;
      float Y = 2.0f * acc[r];
      float d = X - Y;
      unsigned int du = __float_as_uint(d);
      unsigned int sortable = (du & 0x80000000u) ? ~du : (du | 0x80000000u);
      kred[r][tid] = ((unsigned long long)sortable << 32) | (unsigned int)j;
    }
    __syncthreads();
    for (int o = 128; o > 0; o >>= 1) {
      if (tid < o) {
#pragma unroll
        for (int r = 0; r < RPB; ++r) {
          unsigned long long ok = kred[r][tid + o];
          if (ok < kred[r][tid]) kred[r][tid] = ok;
        }
      }
      __syncthreads();
    }
    if (tid < RPB && base + tid < cnt)
      atomicMin(&keys[base + tid], kred[tid][0]);
    __syncthreads();
  }
}

// Apply repair winners to idx / counts.
__global__ void k_fix(const int* __restrict__ nflag, const int* __restrict__ worklist,
                      const unsigned long long* __restrict__ keys,
                      int* __restrict__ idx_i, float* __restrict__ idx_f,
                      int* __restrict__ counts) {
  int cnt = nflag[0];
  if (cnt > WLCAP) cnt = WLCAP;
  int wi = blockIdx.x * blockDim.x + threadIdx.x;
  if (wi < cnt) {
    int n = worklist[wi];
    unsigned long long key = keys[wi];
    int nw = (int)(key & 0xFFFFFFFFull);
    int old = idx_i[n];
    if (nw != old) {
      idx_i[n] = nw; idx_f[n] = (float)nw;
      atomicAdd(&counts[old], -1);
      atomicAdd(&counts[nw], 1);
    }
  }
}

// Tiled gather fused with direct SSE. Write-out vectorized: thread owns t-quad
// r4 = tid&7 and 8 c-values; one float4 z load + one float4 zq store per c
// (4x fewer VMEM ops than scalar; 128B-contiguous per 8-lane group).
__launch_bounds__(256, 4)
__global__ void k_gather(const float* __restrict__ z, const float* __restrict__ emb,
                         const int* __restrict__ idxv, float* __restrict__ zq,
                         float* __restrict__ sse) {
  __shared__ int ids[32];
  __shared__ float tile[32 * 260];
  __shared__ float wsum[4];
  const int tid = threadIdx.x;
  const int blk = blockIdx.x;
  const int b = blk >> 6;
  const int t0 = (blk & 63) << 5;
  const int n0 = (b << 11) + t0;
  if (tid < 32) ids[tid] = idxv[n0 + tid];
  __syncthreads();
  const int r = tid & 31;   // t within tile (staging)
  const int q = tid >> 5;   // c-quarter 0..7 (staging)
  {
    const float4* er = reinterpret_cast<const float4*>(emb) + ((size_t)ids[r] << 6) + (q << 3);
    float4* dst = reinterpret_cast<float4*>(&tile[r * 260 + (q << 5)]);
#pragma unroll
    for (int j = 0; j < 8; ++j) dst[j] = er[j];
  }
  __syncthreads();
  const int r4 = tid & 7;   // t-quad: t = t0 + 4*r4 + j
  const int c0 = tid >> 3;  // base c; covers c = c0 + 32*jc
  float local = 0.f;
  const size_t base = (((size_t)b << 8) << 11) + t0;  // float index of (b, c=0, t0)
  const float4* z4 = reinterpret_cast<const float4*>(z);
  float4* zq4 = reinterpret_cast<float4*>(zq);
#pragma unroll
  for (int jc = 0; jc < 8; ++jc) {
    const int c = c0 + (jc << 5);
    float4 qv;
    qv.x = tile[(4 * r4 + 0) * 260 + c];
    qv.y = tile[(4 * r4 + 1) * 260 + c];
    qv.z = tile[(4 * r4 + 2) * 260 + c];
    qv.w = tile[(4 * r4 + 3) * 260 + c];
    const size_t g4 = ((base + ((size_t)c << 11)) >> 2) + r4;
    float4 zv = z4[g4];
    zq4[g4] = qv;
    float dx = qv.x - zv.x, dy = qv.y - zv.y, dz = qv.z - zv.z, dw = qv.w - zv.w;
    local = fmaf(dx, dx, local); local = fmaf(dy, dy, local);
    local = fmaf(dz, dz, local); local = fmaf(dw, dw, local);
  }
#pragma unroll
  for (int m = 32; m > 0; m >>= 1) local += __shfl_down(local, m);
  if ((tid & 63) == 0) wsum[tid >> 6] = local;
  __syncthreads();
  if (tid == 0) atomicAdd(sse, wsum[0] + wsum[1] + wsum[2] + wsum[3]);
}

__global__ void k_final(const int* __restrict__ counts, const float* __restrict__ sse,
                        float* __restrict__ out_loss, float* __restrict__ out_perp) {
  __shared__ float red[256];
  int tid = threadIdx.x;
  float s = 0.f;
  for (int j = tid; j < NE_; j += 256) {
    float em = (float)counts[j] * (1.0f / (float)N_);
    s += em * logf(em + 1e-10f);
  }
  red[tid] = s;
  __syncthreads();
  for (int o = 128; o > 0; o >>= 1) {
    if (tid < o) red[tid] += red[tid + o];
    __syncthreads();
  }
  if (tid == 0) {
    out_perp[0] = expf(-red[0]);
    out_loss[0] = (0.25f + 1.0f) * sse[0] / (float)NELEM;
  }
}

extern "C" void kernel_launch(void* const* d_in, const int* in_sizes, int n_in,
                              void* d_out, int out_size, void* d_ws, size_t ws_size,
                              hipStream_t stream) {
  const float* z = (const float*)d_in[0];
  const float* emb = (const float*)d_in[1];
  float* out = (float*)d_out;
  float* zq_out = out;
  float* out_loss = out + NELEM;
  float* out_perp = out + NELEM + 1;
  float* out_idx = out + NELEM + 2;

  int* ws_counts = (int*)d_ws;
  float* ws_enorm = (float*)d_ws + 1024;
  float* ws_sse = (float*)d_ws + 2048;
  int* ws_nflag = (int*)d_ws + 2049;
  unsigned long long* ws_keys = (unsigned long long*)((float*)d_ws + 2056);
  int* ws_idx = (int*)d_ws + 18440;
  int* ws_worklist = (int*)d_ws + 83976;
  float* ws_szf = (float*)d_ws + 92168;
  half8* ws_ebuf = (half8*)((float*)d_ws + 100360);
  float* ws_et = (float*)d_ws + 231432;
  float* ws_zstage = (float*)d_ws + 493576;
  float* ws_scores = (float*)d_ws + 2590728;

  k_init<<<73, 256, 0, stream>>>((unsigned int*)d_ws);
  k_prep<<<NE_ / 64, 64, 0, stream>>>(emb, ws_ebuf, ws_enorm, ws_et);
  k_vq<<<N_ / 128, 256, 0, stream>>>(z, ws_ebuf, ws_enorm, ws_idx, out_idx,
                                     ws_counts, ws_nflag, ws_worklist, ws_scores);
  k_zstage<<<2048, 256, 0, stream>>>(z, ws_nflag, ws_worklist, ws_zstage, ws_szf);
  k_repair<<<2048, 256, 0, stream>>>(ws_zstage, ws_szf, ws_et, ws_enorm,
                                     ws_nflag, ws_worklist, ws_keys);
  k_fix<<<WLCAP / 256, 256, 0, stream>>>(ws_nflag, ws_worklist, ws_keys,
                                         ws_idx, out_idx, ws_counts);
  k_gather<<<2048, 256, 0, stream>>>(z, emb, ws_idx, zq_out, ws_sse);
  k_final<<<1, 256, 0, stream>>>(ws_counts, ws_sse, out_loss, out_perp);
}